// Round 2
// baseline (150.181 us; speedup 1.0000x reference)
//
#include <hip/hip_runtime.h>

typedef __attribute__((ext_vector_type(4))) float f32x4;
typedef __attribute__((ext_vector_type(8))) short bf16x8;

__device__ __forceinline__ short f2bf(float f) {
    union { float f; unsigned u; } v; v.f = f;
    unsigned u = v.u + 0x7FFFu + ((v.u >> 16) & 1u);   // RNE
    return (short)(u >> 16);
}
__device__ __forceinline__ int pack_bf2(float a, float b) {
    union { float f; unsigned u; } ua, ub; ua.f = a; ub.f = b;
    unsigned x = ua.u + 0x8000u, y = ub.u + 0x8000u;   // round half-up
    return (int)__builtin_amdgcn_perm(y, x, 0x07060302u);
}
__device__ __forceinline__ float bflo(int p) {
    union { int i; float f; } v; v.i = p << 16; return v.f;
}
__device__ __forceinline__ float bfhi(int p) {
    union { int i; float f; } v; v.i = p & 0xffff0000; return v.f;
}

// sum over lanes {l, l^16, l^32, l^48}.
// gfx950 permlane{16,32}_swap keeps this on the VALU pipe (no DS traffic);
// bitwise-identical to the shfl_xor version (commutative pair adds).
#if __has_builtin(__builtin_amdgcn_permlane16_swap) && \
    __has_builtin(__builtin_amdgcn_permlane32_swap)
__device__ __forceinline__ float quad_sum(float dp) {
    unsigned u = __float_as_uint(dp);
    auto r1 = __builtin_amdgcn_permlane16_swap(u, u, false, false);
    float s = __uint_as_float(r1[0]) + __uint_as_float(r1[1]);
    unsigned v = __float_as_uint(s);
    auto r2 = __builtin_amdgcn_permlane32_swap(v, v, false, false);
    return __uint_as_float(r2[0]) + __uint_as_float(r2[1]);
}
#else
__device__ __forceinline__ float quad_sum(float dp) {
    dp += __shfl_xor(dp, 16, 64);
    dp += __shfl_xor(dp, 32, 64);
    return dp;
}
#endif

// ---------------------------------------------------------------------------
// Prep (16 blocks x 256):
//  AbP16: per c, frag f=(rt*2+kc)*64+L holds A_c[pi(rt*16+(L&15))][32kc+8(L>>4)+j]
//  biasP: fp32, row-permuted: biasP[c][p] = -2*(A_c m_c)[pi(p)]  (C-init term)
//  kscal: m^T A m
// ---------------------------------------------------------------------------
__global__ void gmm_prep(const float* __restrict__ Ainv,
                         const float* __restrict__ means,
                         short* __restrict__ AbP16,
                         float* __restrict__ biasP,
                         float* __restrict__ kscal) {
    __shared__ float sA[64 * 68];
    __shared__ float sm[64];
    __shared__ float sb[64];
    const int c = blockIdx.x, t = threadIdx.x;
    const float* A = Ainv + c * 4096;
    #pragma unroll
    for (int i = 0; i < 4; ++i) {
        int flat = i * 1024 + t * 4;
        int r = flat >> 6, col = flat & 63;
        *(f32x4*)&sA[r * 68 + col] = *(const f32x4*)(A + flat);
    }
    if (t < 64) sm[t] = means[c * 64 + t];
    __syncthreads();
    {   // b[j] = A[j,:].m  (4 lanes per row)
        int j = t >> 2, seg = t & 3;
        float p = 0.f;
        #pragma unroll
        for (int k = 0; k < 16; ++k) p += sA[j * 68 + seg * 16 + k] * sm[seg * 16 + k];
        p += __shfl_xor(p, 1, 64); p += __shfl_xor(p, 2, 64);
        if ((t & 3) == 0) sb[j] = p;
    }
    __syncthreads();
    if (t < 64) {
        float km = sm[t] * sb[t];
        #pragma unroll
        for (int off = 32; off >= 1; off >>= 1) km += __shfl_xor(km, off, 64);
        if (t == 0) kscal[c] = km;
        int rt = t >> 4, qh = (t >> 2) & 3, r = t & 3;
        int pj = (rt >> 1) * 32 + 8 * qh + 4 * (rt & 1) + r;
        biasP[c * 64 + t] = -2.f * sb[pj];
    }
    #pragma unroll
    for (int rep = 0; rep < 2; ++rep) {     // permuted A fragments
        int f = rep * 256 + t;
        int rt = f >> 7, kc = (f >> 6) & 1, L = f & 63;
        int ln = L & 15, q = L >> 4;
        int pj = (rt >> 1) * 32 + 8 * (ln >> 2) + 4 * (rt & 1) + (ln & 3);
        const float* src = &sA[pj * 68 + 32 * kc + 8 * q];
        bf16x8 v;
        #pragma unroll
        for (int j = 0; j < 8; ++j) v[j] = f2bf(src[j]);
        *(bf16x8*)(AbP16 + c * 4096 + f * 8) = v;
    }
}

union BFrag { bf16x8 v; int i[4]; };

// ---------------------------------------------------------------------------
// Main (1024 blocks x 256): 4 waves x 64 samples; x packed bf16 persistent in
// regs (32 VGPRs). A staged in LDS 4 comps at a time (32 KB). T14 split:
// next group's A-frags prefetched into registers BEFORE the 4-comp compute,
// written to LDS after the barrier (HBM latency hidden under compute).
// Quad reduction via permlane{16,32}_swap (VALU pipe, no DS traffic).
// Every lane holds the full slog; coalesced 64-wide store.
// ---------------------------------------------------------------------------
__global__ __launch_bounds__(256) void gmm_main(
    const float* __restrict__ X,
    const float* __restrict__ weights,
    const short* __restrict__ AbP16,
    const float* __restrict__ biasP,
    const float* __restrict__ kscal,
    float* __restrict__ out) {

    __shared__ short sAb[16384];          // 32 KB: 4 comps x 8 KB
    __shared__ float sBias[16 * 64];      // 4 KB, permuted rows
    __shared__ float sKW[32];             // [0..15]=kscal, [16..31]=w

    const int tid = threadIdx.x;
    const int lane = tid & 63, w = tid >> 6;
    const int q = lane >> 4, ln = lane & 15;
    const int base = blockIdx.x * 256 + w * 64;

    // stage 0 A-frags + bias + kw (register-staged, known-good path)
    #pragma unroll
    for (int i = 0; i < 8; ++i)
        ((int4*)sAb)[i * 256 + tid] = ((const int4*)AbP16)[i * 256 + tid];
    ((f32x4*)sBias)[tid] = ((const f32x4*)biasP)[tid];
    if (tid < 16) { sKW[tid] = kscal[tid]; sKW[16 + tid] = weights[tid]; }

    // x -> persistent packed bf16 B-frags (transient fp32 per tile)
    BFrag xb[4][2];
    #pragma unroll
    for (int t = 0; t < 4; ++t) {
        const float* xr = X + (size_t)(base + t * 16 + ln) * 64 + 8 * q;
        #pragma unroll
        for (int kc = 0; kc < 2; ++kc) {
            f32x4 a = *(const f32x4*)(xr + 32 * kc);
            f32x4 b = *(const f32x4*)(xr + 32 * kc + 4);
            xb[t][kc].i[0] = pack_bf2(a[0], a[1]);
            xb[t][kc].i[1] = pack_bf2(a[2], a[3]);
            xb[t][kc].i[2] = pack_bf2(b[0], b[1]);
            xb[t][kc].i[3] = pack_bf2(b[2], b[3]);
        }
    }
    __syncthreads();

    float slog[4] = {0.f, 0.f, 0.f, 0.f};
    int4 pf[8];                           // T14 prefetch registers

    #pragma unroll 1
    for (int g = 0; g < 4; ++g) {
        if (g < 3) {                      // issue next-group loads early
            const int4* src = (const int4*)(AbP16 + (g + 1) * 16384);
            #pragma unroll
            for (int i = 0; i < 8; ++i) pf[i] = src[i * 256 + tid];
        }
        #pragma unroll 1
        for (int cl = 0; cl < 4; ++cl) {
            const int c = g * 4 + cl;
            bf16x8 af[8];
            #pragma unroll
            for (int f = 0; f < 8; ++f)
                af[f] = *(const bf16x8*)&sAb[cl * 4096 + f * 512 + lane * 8];
            f32x4 bias[4];
            #pragma unroll
            for (int rt = 0; rt < 4; ++rt)
                bias[rt] = *(const f32x4*)&sBias[c * 64 + rt * 16 + q * 4];
            const float kc_ = sKW[c], wcc = sKW[16 + c];

            #pragma unroll
            for (int t = 0; t < 4; ++t) {
                float dp0 = 0.f, dp1 = 0.f;
                #pragma unroll
                for (int rt = 0; rt < 4; ++rt) {
                    f32x4 acc = __builtin_amdgcn_mfma_f32_16x16x32_bf16(
                        af[rt * 2 + 0], xb[t][0].v, bias[rt], 0, 0, 0);
                    acc = __builtin_amdgcn_mfma_f32_16x16x32_bf16(
                        af[rt * 2 + 1], xb[t][1].v, acc, 0, 0, 0);
                    int pa = xb[t][rt >> 1].i[(rt & 1) * 2];
                    int pb = xb[t][rt >> 1].i[(rt & 1) * 2 + 1];
                    float pr = acc[0] * bflo(pa) + acc[1] * bfhi(pa)
                             + acc[2] * bflo(pb) + acc[3] * bfhi(pb);
                    if (rt & 1) dp1 += pr; else dp0 += pr;
                }
                float dp = quad_sum(dp0 + dp1);
                float d = fmaxf(dp + kc_, 1e-30f);
                slog[t] = fmaf(wcc, __builtin_amdgcn_logf(d), slog[t]);
            }
        }
        if (g < 3) {                      // write prefetched regs to LDS
            __syncthreads();
            #pragma unroll
            for (int i = 0; i < 8; ++i)
                ((int4*)sAb)[i * 256 + tid] = pf[i];
            __syncthreads();
        }
    }

    // slog[] is bit-identical across lanes after quad_sum: lane (q,ln)
    // writes sample q*16+ln -> one coalesced 64-wide store per wave
    float s0 = (q & 1) ? slog[1] : slog[0];
    float s1 = (q & 1) ? slog[3] : slog[2];
    float sv = (q & 2) ? s1 : s0;
    out[base + lane] = __builtin_amdgcn_exp2f(sv);
}

extern "C" void kernel_launch(void* const* d_in, const int* in_sizes, int n_in,
                              void* d_out, int out_size, void* d_ws, size_t ws_size,
                              hipStream_t stream) {
    const float* X       = (const float*)d_in[0];
    const float* Ainv    = (const float*)d_in[1];
    const float* means   = (const float*)d_in[2];
    const float* weights = (const float*)d_in[3];
    float* out = (float*)d_out;
    const int N = in_sizes[0] / 64;

    short* AbP16 = (short*)d_ws;                       // 131072 B
    float* biasP = (float*)((char*)d_ws + 131072);     // 4096 B
    float* kscal = (float*)((char*)d_ws + 135168);     // 64 B

    gmm_prep<<<dim3(16), dim3(256), 0, stream>>>(Ainv, means, AbP16, biasP, kscal);
    gmm_main<<<dim3(N / 256), dim3(256), 0, stream>>>(X, weights, AbP16, biasP, kscal, out);
}

// Round 3
// 129.354 us; speedup vs baseline: 1.1610x; 1.1610x over previous
//
#include <hip/hip_runtime.h>

typedef __attribute__((ext_vector_type(4))) float f32x4;
typedef __attribute__((ext_vector_type(8))) short bf16x8;

__device__ __forceinline__ short f2bf(float f) {
    union { float f; unsigned u; } v; v.f = f;
    unsigned u = v.u + 0x7FFFu + ((v.u >> 16) & 1u);   // RNE
    return (short)(u >> 16);
}
__device__ __forceinline__ int pack_bf2(float a, float b) {
    union { float f; unsigned u; } ua, ub; ua.f = a; ub.f = b;
    unsigned x = ua.u + 0x8000u, y = ub.u + 0x8000u;   // round half-up
    return (int)__builtin_amdgcn_perm(y, x, 0x07060302u);
}
__device__ __forceinline__ float bflo(int p) {
    union { int i; float f; } v; v.i = p << 16; return v.f;
}
__device__ __forceinline__ float bfhi(int p) {
    union { int i; float f; } v; v.i = p & 0xffff0000; return v.f;
}

// sum over lanes {l, l^16, l^32, l^48}.
// gfx950 permlane{16,32}_swap keeps this on the VALU pipe (no DS traffic);
// bitwise-identical to the shfl_xor version (same pair-add order).
// Verified correct on-HW in round 2 (masked by an unrelated spill).
#if __has_builtin(__builtin_amdgcn_permlane16_swap) && \
    __has_builtin(__builtin_amdgcn_permlane32_swap)
__device__ __forceinline__ float quad_sum(float dp) {
    unsigned u = __float_as_uint(dp);
    auto r1 = __builtin_amdgcn_permlane16_swap(u, u, false, false);
    float s = __uint_as_float(r1[0]) + __uint_as_float(r1[1]);
    unsigned v = __float_as_uint(s);
    auto r2 = __builtin_amdgcn_permlane32_swap(v, v, false, false);
    return __uint_as_float(r2[0]) + __uint_as_float(r2[1]);
}
#else
__device__ __forceinline__ float quad_sum(float dp) {
    dp += __shfl_xor(dp, 16, 64);
    dp += __shfl_xor(dp, 32, 64);
    return dp;
}
#endif

// ---------------------------------------------------------------------------
// Prep (16 blocks x 256):
//  AbP16: per c, frag f=(rt*2+kc)*64+L holds A_c[pi(rt*16+(L&15))][32kc+8(L>>4)+j]
//  biasP: fp32, row-permuted: biasP[c][p] = -2*(A_c m_c)[pi(p)]  (C-init term)
//  kscal: m^T A m
// ---------------------------------------------------------------------------
__global__ void gmm_prep(const float* __restrict__ Ainv,
                         const float* __restrict__ means,
                         short* __restrict__ AbP16,
                         float* __restrict__ biasP,
                         float* __restrict__ kscal) {
    __shared__ float sA[64 * 68];
    __shared__ float sm[64];
    __shared__ float sb[64];
    const int c = blockIdx.x, t = threadIdx.x;
    const float* A = Ainv + c * 4096;
    #pragma unroll
    for (int i = 0; i < 4; ++i) {
        int flat = i * 1024 + t * 4;
        int r = flat >> 6, col = flat & 63;
        *(f32x4*)&sA[r * 68 + col] = *(const f32x4*)(A + flat);
    }
    if (t < 64) sm[t] = means[c * 64 + t];
    __syncthreads();
    {   // b[j] = A[j,:].m  (4 lanes per row)
        int j = t >> 2, seg = t & 3;
        float p = 0.f;
        #pragma unroll
        for (int k = 0; k < 16; ++k) p += sA[j * 68 + seg * 16 + k] * sm[seg * 16 + k];
        p += __shfl_xor(p, 1, 64); p += __shfl_xor(p, 2, 64);
        if ((t & 3) == 0) sb[j] = p;
    }
    __syncthreads();
    if (t < 64) {
        float km = sm[t] * sb[t];
        #pragma unroll
        for (int off = 32; off >= 1; off >>= 1) km += __shfl_xor(km, off, 64);
        if (t == 0) kscal[c] = km;
        int rt = t >> 4, qh = (t >> 2) & 3, r = t & 3;
        int pj = (rt >> 1) * 32 + 8 * qh + 4 * (rt & 1) + r;
        biasP[c * 64 + t] = -2.f * sb[pj];
    }
    #pragma unroll
    for (int rep = 0; rep < 2; ++rep) {     // permuted A fragments
        int f = rep * 256 + t;
        int rt = f >> 7, kc = (f >> 6) & 1, L = f & 63;
        int ln = L & 15, q = L >> 4;
        int pj = (rt >> 1) * 32 + 8 * (ln >> 2) + 4 * (rt & 1) + (ln & 3);
        const float* src = &sA[pj * 68 + 32 * kc + 8 * q];
        bf16x8 v;
        #pragma unroll
        for (int j = 0; j < 8; ++j) v[j] = f2bf(src[j]);
        *(bf16x8*)(AbP16 + c * 4096 + f * 8) = v;
    }
}

union BFrag { bf16x8 v; int i[4]; };

// ---------------------------------------------------------------------------
// Main (1024 blocks x 256): 4 waves x 64 samples; x packed bf16 persistent in
// regs (32 VGPRs). A staged in LDS 4 comps at a time (32 KB, 4 stages,
// register-staged — known-good path, no prefetch regs: we are at the 128-VGPR
// occupancy boundary with only ~16 regs headroom).
// Quad reduction via permlane{16,32}_swap (VALU pipe, no DS traffic).
// Every lane holds full slog; coalesced 64-wide store.
// ---------------------------------------------------------------------------
__global__ __launch_bounds__(256) void gmm_main(
    const float* __restrict__ X,
    const float* __restrict__ weights,
    const short* __restrict__ AbP16,
    const float* __restrict__ biasP,
    const float* __restrict__ kscal,
    float* __restrict__ out) {

    __shared__ short sAb[16384];          // 32 KB: 4 comps x 8 KB
    __shared__ float sBias[16 * 64];      // 4 KB, permuted rows
    __shared__ float sKW[32];             // [0..15]=kscal, [16..31]=w

    const int tid = threadIdx.x;
    const int lane = tid & 63, w = tid >> 6;
    const int q = lane >> 4, ln = lane & 15;
    const int base = blockIdx.x * 256 + w * 64;

    // stage 0 A-frags + bias + kw (register-staged, known-good path)
    #pragma unroll
    for (int i = 0; i < 8; ++i)
        ((int4*)sAb)[i * 256 + tid] = ((const int4*)AbP16)[i * 256 + tid];
    ((f32x4*)sBias)[tid] = ((const f32x4*)biasP)[tid];
    if (tid < 16) { sKW[tid] = kscal[tid]; sKW[16 + tid] = weights[tid]; }

    // x -> persistent packed bf16 B-frags (transient fp32 per tile)
    BFrag xb[4][2];
    #pragma unroll
    for (int t = 0; t < 4; ++t) {
        const float* xr = X + (size_t)(base + t * 16 + ln) * 64 + 8 * q;
        #pragma unroll
        for (int kc = 0; kc < 2; ++kc) {
            f32x4 a = *(const f32x4*)(xr + 32 * kc);
            f32x4 b = *(const f32x4*)(xr + 32 * kc + 4);
            xb[t][kc].i[0] = pack_bf2(a[0], a[1]);
            xb[t][kc].i[1] = pack_bf2(a[2], a[3]);
            xb[t][kc].i[2] = pack_bf2(b[0], b[1]);
            xb[t][kc].i[3] = pack_bf2(b[2], b[3]);
        }
    }
    __syncthreads();

    float slog[4] = {0.f, 0.f, 0.f, 0.f};

    #pragma unroll 1
    for (int g = 0; g < 4; ++g) {
        #pragma unroll 1
        for (int cl = 0; cl < 4; ++cl) {
            const int c = g * 4 + cl;
            bf16x8 af[8];
            #pragma unroll
            for (int f = 0; f < 8; ++f)
                af[f] = *(const bf16x8*)&sAb[cl * 4096 + f * 512 + lane * 8];
            f32x4 bias[4];
            #pragma unroll
            for (int rt = 0; rt < 4; ++rt)
                bias[rt] = *(const f32x4*)&sBias[c * 64 + rt * 16 + q * 4];
            const float kc_ = sKW[c], wcc = sKW[16 + c];

            #pragma unroll
            for (int t = 0; t < 4; ++t) {
                float dp0 = 0.f, dp1 = 0.f;
                #pragma unroll
                for (int rt = 0; rt < 4; ++rt) {
                    f32x4 acc = __builtin_amdgcn_mfma_f32_16x16x32_bf16(
                        af[rt * 2 + 0], xb[t][0].v, bias[rt], 0, 0, 0);
                    acc = __builtin_amdgcn_mfma_f32_16x16x32_bf16(
                        af[rt * 2 + 1], xb[t][1].v, acc, 0, 0, 0);
                    int pa = xb[t][rt >> 1].i[(rt & 1) * 2];
                    int pb = xb[t][rt >> 1].i[(rt & 1) * 2 + 1];
                    float pr = acc[0] * bflo(pa) + acc[1] * bfhi(pa)
                             + acc[2] * bflo(pb) + acc[3] * bfhi(pb);
                    if (rt & 1) dp1 += pr; else dp0 += pr;
                }
                float dp = quad_sum(dp0 + dp1);
                float d = fmaxf(dp + kc_, 1e-30f);
                slog[t] = fmaf(wcc, __builtin_amdgcn_logf(d), slog[t]);
            }
        }
        if (g < 3) {                      // restage next 4 comps
            __syncthreads();
            const int4* src = (const int4*)(AbP16 + (g + 1) * 16384);
            #pragma unroll
            for (int i = 0; i < 8; ++i)
                ((int4*)sAb)[i * 256 + tid] = src[i * 256 + tid];
            __syncthreads();
        }
    }

    // slog[] is identical across each quad after quad_sum: lane (q,ln)
    // writes sample q*16+ln -> one coalesced 64-wide store per wave
    float s0 = (q & 1) ? slog[1] : slog[0];
    float s1 = (q & 1) ? slog[3] : slog[2];
    float sv = (q & 2) ? s1 : s0;
    out[base + lane] = __builtin_amdgcn_exp2f(sv);
}

extern "C" void kernel_launch(void* const* d_in, const int* in_sizes, int n_in,
                              void* d_out, int out_size, void* d_ws, size_t ws_size,
                              hipStream_t stream) {
    const float* X       = (const float*)d_in[0];
    const float* Ainv    = (const float*)d_in[1];
    const float* means   = (const float*)d_in[2];
    const float* weights = (const float*)d_in[3];
    float* out = (float*)d_out;
    const int N = in_sizes[0] / 64;

    short* AbP16 = (short*)d_ws;                       // 131072 B
    float* biasP = (float*)((char*)d_ws + 131072);     // 4096 B
    float* kscal = (float*)((char*)d_ws + 135168);     // 64 B

    gmm_prep<<<dim3(16), dim3(256), 0, stream>>>(Ainv, means, AbP16, biasP, kscal);
    gmm_main<<<dim3(N / 256), dim3(256), 0, stream>>>(X, weights, AbP16, biasP, kscal, out);
}

// Round 4
// 128.838 us; speedup vs baseline: 1.1657x; 1.0040x over previous
//
#include <hip/hip_runtime.h>

typedef __attribute__((ext_vector_type(4))) float f32x4;
typedef __attribute__((ext_vector_type(8))) short bf16x8;

__device__ __forceinline__ short f2bf(float f) {
    union { float f; unsigned u; } v; v.f = f;
    unsigned u = v.u + 0x7FFFu + ((v.u >> 16) & 1u);   // RNE
    return (short)(u >> 16);
}
__device__ __forceinline__ int pack_bf2(float a, float b) {
    union { float f; unsigned u; } ua, ub; ua.f = a; ub.f = b;
    unsigned x = ua.u + 0x8000u, y = ub.u + 0x8000u;   // round half-up
    return (int)__builtin_amdgcn_perm(y, x, 0x07060302u);
}
__device__ __forceinline__ float bflo(int p) {
    union { int i; float f; } v; v.i = p << 16; return v.f;
}
__device__ __forceinline__ float bfhi(int p) {
    union { int i; float f; } v; v.i = p & 0xffff0000; return v.f;
}

// sum over lanes {l, l^16, l^32, l^48}.
// gfx950 permlane{16,32}_swap keeps this on the VALU pipe (no DS traffic);
// bitwise-identical to the shfl_xor version. Verified on-HW (round 3).
#if __has_builtin(__builtin_amdgcn_permlane16_swap) && \
    __has_builtin(__builtin_amdgcn_permlane32_swap)
__device__ __forceinline__ float quad_sum(float dp) {
    unsigned u = __float_as_uint(dp);
    auto r1 = __builtin_amdgcn_permlane16_swap(u, u, false, false);
    float s = __uint_as_float(r1[0]) + __uint_as_float(r1[1]);
    unsigned v = __float_as_uint(s);
    auto r2 = __builtin_amdgcn_permlane32_swap(v, v, false, false);
    return __uint_as_float(r2[0]) + __uint_as_float(r2[1]);
}
#else
__device__ __forceinline__ float quad_sum(float dp) {
    dp += __shfl_xor(dp, 16, 64);
    dp += __shfl_xor(dp, 32, 64);
    return dp;
}
#endif

// ---------------------------------------------------------------------------
// Prep (16 blocks x 256):
//  AbP16: per c, frag f=(rt*2+kc)*64+L holds A_c[pi(rt*16+(L&15))][32kc+8(L>>4)+j]
//  biasP: fp32, row-permuted: biasP[c][p] = -2*(A_c m_c)[pi(p)]  (C-init term)
//  kscal: m^T A m
// ---------------------------------------------------------------------------
__global__ void gmm_prep(const float* __restrict__ Ainv,
                         const float* __restrict__ means,
                         short* __restrict__ AbP16,
                         float* __restrict__ biasP,
                         float* __restrict__ kscal) {
    __shared__ float sA[64 * 68];
    __shared__ float sm[64];
    __shared__ float sb[64];
    const int c = blockIdx.x, t = threadIdx.x;
    const float* A = Ainv + c * 4096;
    #pragma unroll
    for (int i = 0; i < 4; ++i) {
        int flat = i * 1024 + t * 4;
        int r = flat >> 6, col = flat & 63;
        *(f32x4*)&sA[r * 68 + col] = *(const f32x4*)(A + flat);
    }
    if (t < 64) sm[t] = means[c * 64 + t];
    __syncthreads();
    {   // b[j] = A[j,:].m  (4 lanes per row)
        int j = t >> 2, seg = t & 3;
        float p = 0.f;
        #pragma unroll
        for (int k = 0; k < 16; ++k) p += sA[j * 68 + seg * 16 + k] * sm[seg * 16 + k];
        p += __shfl_xor(p, 1, 64); p += __shfl_xor(p, 2, 64);
        if ((t & 3) == 0) sb[j] = p;
    }
    __syncthreads();
    if (t < 64) {
        float km = sm[t] * sb[t];
        #pragma unroll
        for (int off = 32; off >= 1; off >>= 1) km += __shfl_xor(km, off, 64);
        if (t == 0) kscal[c] = km;
        int rt = t >> 4, qh = (t >> 2) & 3, r = t & 3;
        int pj = (rt >> 1) * 32 + 8 * qh + 4 * (rt & 1) + r;
        biasP[c * 64 + t] = -2.f * sb[pj];
    }
    #pragma unroll
    for (int rep = 0; rep < 2; ++rep) {     // permuted A fragments
        int f = rep * 256 + t;
        int rt = f >> 7, kc = (f >> 6) & 1, L = f & 63;
        int ln = L & 15, q = L >> 4;
        int pj = (rt >> 1) * 32 + 8 * (ln >> 2) + 4 * (rt & 1) + (ln & 3);
        const float* src = &sA[pj * 68 + 32 * kc + 8 * q];
        bf16x8 v;
        #pragma unroll
        for (int j = 0; j < 8; ++j) v[j] = f2bf(src[j]);
        *(bf16x8*)(AbP16 + c * 4096 + f * 8) = v;
    }
}

union BFrag { bf16x8 v; int i[4]; };

// ---------------------------------------------------------------------------
// Main (1024 blocks x 256): 4 waves x 64 samples; x packed bf16 persistent in
// regs (32 VGPRs). NO LDS, NO barriers: A-fragments (128 KB total, L2/L3-
// resident, shared by all blocks) are read per comp straight from global —
// L2-broadcast beats the contended DS pipe (16 waves/CU x 192 ds_read_b128
// was ~37k cyc/CU, the busiest pipe). Per comp per wave: 8 coalesced
// dwordx4 af loads (1 KB/instr) + 4 bias loads + 2 uniform scalar loads.
// Quad reduction via permlane{16,32}_swap; coalesced 64-wide store.
// ---------------------------------------------------------------------------
__global__ __launch_bounds__(256, 4) void gmm_main(
    const float* __restrict__ X,
    const float* __restrict__ weights,
    const short* __restrict__ AbP16,
    const float* __restrict__ biasP,
    const float* __restrict__ kscal,
    float* __restrict__ out) {

    const int tid = threadIdx.x;
    const int lane = tid & 63, w = tid >> 6;
    const int q = lane >> 4, ln = lane & 15;
    const int base = blockIdx.x * 256 + w * 64;

    // x -> persistent packed bf16 B-frags (transient fp32 per tile)
    BFrag xb[4][2];
    #pragma unroll
    for (int t = 0; t < 4; ++t) {
        const float* xr = X + (size_t)(base + t * 16 + ln) * 64 + 8 * q;
        #pragma unroll
        for (int kc = 0; kc < 2; ++kc) {
            f32x4 a = *(const f32x4*)(xr + 32 * kc);
            f32x4 b = *(const f32x4*)(xr + 32 * kc + 4);
            xb[t][kc].i[0] = pack_bf2(a[0], a[1]);
            xb[t][kc].i[1] = pack_bf2(a[2], a[3]);
            xb[t][kc].i[2] = pack_bf2(b[0], b[1]);
            xb[t][kc].i[3] = pack_bf2(b[2], b[3]);
        }
    }

    float slog[4] = {0.f, 0.f, 0.f, 0.f};

    #pragma unroll 1
    for (int c = 0; c < 16; ++c) {
        const short* aP = AbP16 + c * 4096 + lane * 8;
        bf16x8 af[8];
        #pragma unroll
        for (int f = 0; f < 8; ++f)
            af[f] = *(const bf16x8*)(aP + f * 512);
        f32x4 bias[4];
        #pragma unroll
        for (int rt = 0; rt < 4; ++rt)
            bias[rt] = *(const f32x4*)(biasP + c * 64 + rt * 16 + q * 4);
        const float kc_ = kscal[c], wcc = weights[c];   // uniform -> s_load

        #pragma unroll
        for (int t = 0; t < 4; ++t) {
            float dp0 = 0.f, dp1 = 0.f;
            #pragma unroll
            for (int rt = 0; rt < 4; ++rt) {
                f32x4 acc = __builtin_amdgcn_mfma_f32_16x16x32_bf16(
                    af[rt * 2 + 0], xb[t][0].v, bias[rt], 0, 0, 0);
                acc = __builtin_amdgcn_mfma_f32_16x16x32_bf16(
                    af[rt * 2 + 1], xb[t][1].v, acc, 0, 0, 0);
                int pa = xb[t][rt >> 1].i[(rt & 1) * 2];
                int pb = xb[t][rt >> 1].i[(rt & 1) * 2 + 1];
                float pr = acc[0] * bflo(pa) + acc[1] * bfhi(pa)
                         + acc[2] * bflo(pb) + acc[3] * bfhi(pb);
                if (rt & 1) dp1 += pr; else dp0 += pr;
            }
            float dp = quad_sum(dp0 + dp1);
            float d = fmaxf(dp + kc_, 1e-30f);
            slog[t] = fmaf(wcc, __builtin_amdgcn_logf(d), slog[t]);
        }
    }

    // slog[] identical across each quad after quad_sum: lane (q,ln)
    // writes sample q*16+ln -> one coalesced 64-wide store per wave
    float s0 = (q & 1) ? slog[1] : slog[0];
    float s1 = (q & 1) ? slog[3] : slog[2];
    float sv = (q & 2) ? s1 : s0;
    out[base + lane] = __builtin_amdgcn_exp2f(sv);
}

extern "C" void kernel_launch(void* const* d_in, const int* in_sizes, int n_in,
                              void* d_out, int out_size, void* d_ws, size_t ws_size,
                              hipStream_t stream) {
    const float* X       = (const float*)d_in[0];
    const float* Ainv    = (const float*)d_in[1];
    const float* means   = (const float*)d_in[2];
    const float* weights = (const float*)d_in[3];
    float* out = (float*)d_out;
    const int N = in_sizes[0] / 64;

    short* AbP16 = (short*)d_ws;                       // 131072 B
    float* biasP = (float*)((char*)d_ws + 131072);     // 4096 B
    float* kscal = (float*)((char*)d_ws + 135168);     // 64 B

    gmm_prep<<<dim3(16), dim3(256), 0, stream>>>(Ainv, means, AbP16, biasP, kscal);
    gmm_main<<<dim3(N / 256), dim3(256), 0, stream>>>(X, weights, AbP16, biasP, kscal, out);
}